// Round 3
// baseline (297.867 us; speedup 1.0000x reference)
//
#include <hip/hip_runtime.h>
#include <hip/hip_bf16.h>
#include <stdint.h>

#define NPRIM 65536
#define NT 16
#define T_TILES 256
#define CH 8192

typedef unsigned long long u64;
typedef unsigned int u32;

// ---------------------------------------------------------------------------
// Kernel 1: per-prim bounds (4x4-bit packed), sort key, per-tile histogram
// ---------------------------------------------------------------------------
__global__ __launch_bounds__(256) void k_compute(
    const float2* __restrict__ pos2d, const float* __restrict__ radius,
    const float* __restrict__ depth, u64* __restrict__ keys,
    u32* __restrict__ bounds, u32* __restrict__ counts)
{
    __shared__ u32 hist[T_TILES];
    int tid = threadIdx.x;
    hist[tid] = 0;
    __syncthreads();

    int i = blockIdx.x * 256 + tid;
    float2 p = pos2d[i];
    float r = radius[i];
    const float mx = (float)(16.0 - 1e-5);  // matches python 16 - 1e-5 -> f32
    float fx = p.x / 68.0f;                 // BLOCK_W == BLOCK_H == 68 (ref bug preserved)
    float fy = p.y / 68.0f;
    int xmin = (int)fminf(fmaxf(fx - r, 0.0f), mx);
    int xmax = (int)fminf(fmaxf(fx + r, 0.0f), mx);
    int ymin = (int)fminf(fmaxf(fy - r, 0.0f), mx);
    int ymax = (int)fminf(fmaxf(fy + r, 0.0f), mx);

    bounds[i] = (u32)(xmin | (xmax << 4) | (ymin << 8) | (ymax << 12));
    // depth >= 0 -> float bits order as uint; prim id fits exactly 16 bits
    keys[i] = ((u64)__float_as_uint(depth[i]) << 16) | (u32)i;

    for (int ty = ymin; ty <= ymax; ++ty)
        for (int tx = xmin; tx <= xmax; ++tx)
            atomicAdd(&hist[ty * NT + tx], 1u);
    __syncthreads();
    u32 h = hist[tid];
    if (h) atomicAdd(&counts[tid], h);
}

// ---------------------------------------------------------------------------
// Kernel 2: scan 256 counts -> inclusive tile_count (output) + exclusive offsets
// ---------------------------------------------------------------------------
__global__ __launch_bounds__(256) void k_scan(
    const u32* __restrict__ counts, int* __restrict__ tile_count,
    u32* __restrict__ offsets)
{
    int tid = threadIdx.x;
    int lane = tid & 63, w = tid >> 6;
    u32 c = counts[tid];
    u32 v = c;
    #pragma unroll
    for (int d = 1; d < 64; d <<= 1) {
        u32 t = __shfl_up(v, d, 64);
        if (lane >= d) v += t;
    }
    __shared__ u32 wtot[4];
    if (lane == 63) wtot[w] = v;
    __syncthreads();
    u32 add = 0;
    for (int i = 0; i < w; ++i) add += wtot[i];
    v += add;
    tile_count[tid] = (int)v;     // inclusive cumsum (reference output 0)
    offsets[tid] = v - c;         // exclusive offsets for scatter
}

// ---------------------------------------------------------------------------
// Bitonic sort of 65536 u64 keys (all distinct: low 16 bits = prim id)
// ---------------------------------------------------------------------------
__global__ __launch_bounds__(512) void k_sort_local(u64* __restrict__ keys)
{
    __shared__ u64 s[CH];                      // 64 KB
    int base = blockIdx.x * CH;
    for (int t = threadIdx.x; t < CH; t += 512) s[t] = keys[base + t];
    __syncthreads();
    for (int k = 2; k <= CH; k <<= 1) {
        for (int j = k >> 1; j > 0; j >>= 1) {
            for (int t = threadIdx.x; t < CH / 2; t += 512) {
                int i = ((t & ~(j - 1)) << 1) | (t & (j - 1));
                int p = i | j;
                bool up = (((base + i) & k) == 0);
                u64 a = s[i], b = s[p];
                if ((a > b) == up) { s[i] = b; s[p] = a; }
            }
            __syncthreads();
        }
    }
    for (int t = threadIdx.x; t < CH; t += 512) keys[base + t] = s[t];
}

// Fused global strides 2^13 .. 2^(13+M-1) of merge stage k = 2^(13+M).
// Each thread owns the closed group {ib ^ subset-of-strides} in registers.
template<int M>
__global__ __launch_bounds__(256) void k_merge_global(u64* __restrict__ keys)
{
    int t = blockIdx.x * 256 + threadIdx.x;    // NPRIM >> M groups
    int low = t & (CH - 1);
    int high = t >> 13;
    int ib = (high << (13 + M)) | low;
    bool up = ((ib & (1 << (13 + M))) == 0);
    u64 v[1 << M];
    #pragma unroll
    for (int g = 0; g < (1 << M); ++g) v[g] = keys[ib + (g << 13)];
    #pragma unroll
    for (int p = M - 1; p >= 0; --p) {
        #pragma unroll
        for (int g = 0; g < (1 << M); ++g) {
            if (!(g & (1 << p))) {
                int h = g | (1 << p);
                u64 a = v[g], b = v[h];
                if ((a > b) == up) { v[g] = b; v[h] = a; }
            }
        }
    }
    #pragma unroll
    for (int g = 0; g < (1 << M); ++g) keys[ib + (g << 13)] = v[g];
}

// LDS passes (strides 4096..1) of merge stage k. Final call (entries != null)
// fuses the permutation: entry[s] = bounds[prim]<<16 | prim.
__global__ __launch_bounds__(512) void k_merge_lds(
    u64* __restrict__ keys, int k,
    const u32* __restrict__ bounds, u32* __restrict__ entries)
{
    __shared__ u64 s[CH];
    int base = blockIdx.x * CH;
    for (int t = threadIdx.x; t < CH; t += 512) s[t] = keys[base + t];
    __syncthreads();
    bool up = ((base & k) == 0);
    for (int j = CH >> 1; j > 0; j >>= 1) {
        for (int t = threadIdx.x; t < CH / 2; t += 512) {
            int i = ((t & ~(j - 1)) << 1) | (t & (j - 1));
            int p = i | j;
            u64 a = s[i], b = s[p];
            if ((a > b) == up) { s[i] = b; s[p] = a; }
        }
        __syncthreads();
    }
    if (entries) {
        for (int t = threadIdx.x; t < CH; t += 512) {
            u64 key = s[t];
            u32 pr = (u32)key & 0xFFFFu;
            entries[base + t] = (bounds[pr] << 16) | pr;
        }
    } else {
        for (int t = threadIdx.x; t < CH; t += 512) keys[base + t] = s[t];
    }
}

// ---------------------------------------------------------------------------
// Kernel 4: per-tile ordered compaction. One block per tile; stream the
// depth-sorted entry array (256 KB, L2-resident) and emit members in order.
// ---------------------------------------------------------------------------
__global__ __launch_bounds__(256) void k_compact(
    const uint4* __restrict__ entries4, const u32* __restrict__ offsets,
    int* __restrict__ out_idx)
{
    int tile = blockIdx.x;
    int tx = tile & 15, ty = tile >> 4;
    int tid = threadIdx.x, lane = tid & 63, wave = tid >> 6;
    __shared__ u32 wtot[4];
    u32 base = offsets[tile];
    u64 lmask = (1ull << lane) - 1;

    for (int c = 0; c < NPRIM / 1024; ++c) {   // 64 iterations x 1024 entries
        uint4 e = entries4[c * 256 + tid];     // s = c*1024 + tid*4 + q
        u32 ev[4] = {e.x, e.y, e.z, e.w};
        bool m[4]; u64 bal[4];
        #pragma unroll
        for (int q = 0; q < 4; ++q) {
            u32 b = ev[q] >> 16;
            int xmn = b & 15, xmx = (b >> 4) & 15;
            int ymn = (b >> 8) & 15, ymx = (b >> 12) & 15;
            m[q] = (tx >= xmn) && (tx <= xmx) && (ty >= ymn) && (ty <= ymx);
            bal[q] = __ballot(m[q]);
        }
        u32 wcnt = __popcll(bal[0]) + __popcll(bal[1]) + __popcll(bal[2]) + __popcll(bal[3]);
        if (lane == 0) wtot[wave] = wcnt;
        __syncthreads();
        u32 woff = base;
        for (int w = 0; w < wave; ++w) woff += wtot[w];
        u32 tot = wtot[0] + wtot[1] + wtot[2] + wtot[3];
        // entries of lanes below me (all 4 slots s-ordered: s = lane*4 + q)
        u32 pre = __popcll(bal[0] & lmask) + __popcll(bal[1] & lmask)
                + __popcll(bal[2] & lmask) + __popcll(bal[3] & lmask);
        #pragma unroll
        for (int q = 0; q < 4; ++q) {
            if (m[q]) { out_idx[woff + pre] = (int)(ev[q] & 0xFFFFu); pre++; }
        }
        base += tot;
        __syncthreads();   // wtot reused next iteration
    }
}

// ---------------------------------------------------------------------------
extern "C" void kernel_launch(void* const* d_in, const int* in_sizes, int n_in,
                              void* d_out, int out_size, void* d_ws, size_t ws_size,
                              hipStream_t stream)
{
    const float2* pos2d = (const float2*)d_in[0];
    const float*  radius = (const float*)d_in[1];
    const float*  depth  = (const float*)d_in[2];

    int* out32        = (int*)d_out;
    int* tile_count   = out32;             // [256] inclusive cumsum
    int* tile_indices = out32 + T_TILES;   // [256*65536]

    char* ws = (char*)d_ws;
    u64* keys    = (u64*)(ws);                        // 512 KB
    u32* bounds  = (u32*)(ws + 512 * 1024);           // 256 KB
    u32* entries = (u32*)(ws + 768 * 1024);           // 256 KB
    u32* counts  = (u32*)(ws + 1024 * 1024);          // 1 KB
    u32* offsets = (u32*)(ws + 1024 * 1024 + 4096);   // 1 KB

    hipMemsetAsync(counts, 0, T_TILES * sizeof(u32), stream);
    // -1 padding for the whole index region (0xFFFFFFFF == -1)
    hipMemsetAsync(tile_indices, 0xFF, (size_t)T_TILES * NPRIM * sizeof(int), stream);

    k_compute<<<NPRIM / 256, 256, 0, stream>>>(pos2d, radius, depth, keys, bounds, counts);
    k_scan<<<1, 256, 0, stream>>>(counts, tile_count, offsets);

    // bitonic sort: local 8K chunks, then stages k = 16K, 32K, 64K
    k_sort_local<<<NPRIM / CH, 512, 0, stream>>>(keys);
    k_merge_global<1><<<(NPRIM / 2) / 256, 256, 0, stream>>>(keys);
    k_merge_lds<<<NPRIM / CH, 512, 0, stream>>>(keys, 16384, nullptr, nullptr);
    k_merge_global<2><<<(NPRIM / 4) / 256, 256, 0, stream>>>(keys);
    k_merge_lds<<<NPRIM / CH, 512, 0, stream>>>(keys, 32768, nullptr, nullptr);
    k_merge_global<3><<<(NPRIM / 8) / 256, 256, 0, stream>>>(keys);
    k_merge_lds<<<NPRIM / CH, 512, 0, stream>>>(keys, 65536, bounds, entries);

    k_compact<<<T_TILES, 256, 0, stream>>>((const uint4*)entries, offsets, tile_indices);
}

// Round 4
// 171.684 us; speedup vs baseline: 1.7350x; 1.7350x over previous
//
#include <hip/hip_runtime.h>
#include <hip/hip_bf16.h>
#include <stdint.h>

#define NPRIM 65536
#define NT 16
#define T_TILES 256
#define RBLK 64            // radix/compute blocks (1024 elems each)

typedef unsigned long long u64;
typedef unsigned int u32;

// ---------------------------------------------------------------------------
// Kernel 1: per-prim bounds (4x4-bit packed), sort key, per-tile histogram
// 64 blocks x 256 threads x 4 elems
// ---------------------------------------------------------------------------
__global__ __launch_bounds__(256) void k_compute(
    const float2* __restrict__ pos2d, const float* __restrict__ radius,
    const float* __restrict__ depth, u64* __restrict__ keys,
    u32* __restrict__ bounds, u32* __restrict__ counts)
{
    __shared__ u32 hist[T_TILES];
    int tid = threadIdx.x;
    hist[tid] = 0;
    __syncthreads();

    int base = blockIdx.x * 1024;
    const float mx = (float)(16.0 - 1e-5);  // matches python 16 - 1e-5 -> f32
    #pragma unroll
    for (int q = 0; q < 4; ++q) {
        int i = base + q * 256 + tid;
        float2 p = pos2d[i];
        float r = radius[i];
        float fx = p.x / 68.0f;             // BLOCK_W == BLOCK_H == 68 (ref bug preserved)
        float fy = p.y / 68.0f;
        int xmin = (int)fminf(fmaxf(fx - r, 0.0f), mx);
        int xmax = (int)fminf(fmaxf(fx + r, 0.0f), mx);
        int ymin = (int)fminf(fmaxf(fy - r, 0.0f), mx);
        int ymax = (int)fminf(fmaxf(fy + r, 0.0f), mx);

        bounds[i] = (u32)(xmin | (xmax << 4) | (ymin << 8) | (ymax << 12));
        // depth >= 0 -> float bits order as uint; prim id fits exactly 16 bits
        keys[i] = ((u64)__float_as_uint(depth[i]) << 16) | (u32)i;

        for (int ty = ymin; ty <= ymax; ++ty)
            for (int tx = xmin; tx <= xmax; ++tx)
                atomicAdd(&hist[ty * NT + tx], 1u);
    }
    __syncthreads();
    u32 h = hist[tid];
    if (h) atomicAdd(&counts[tid], h);
}

// ---------------------------------------------------------------------------
// Kernel 2: scan 256 counts -> inclusive tile_count (output) + exclusive offsets
// ---------------------------------------------------------------------------
__global__ __launch_bounds__(256) void k_scan(
    const u32* __restrict__ counts, int* __restrict__ tile_count,
    u32* __restrict__ offsets)
{
    int tid = threadIdx.x;
    int lane = tid & 63, w = tid >> 6;
    u32 c = counts[tid];
    u32 v = c;
    #pragma unroll
    for (int d = 1; d < 64; d <<= 1) {
        u32 t = __shfl_up(v, d, 64);
        if (lane >= d) v += t;
    }
    __shared__ u32 wtot[4];
    if (lane == 63) wtot[w] = v;
    __syncthreads();
    u32 add = 0;
    for (int i = 0; i < w; ++i) add += wtot[i];
    v += add;
    tile_count[tid] = (int)v;     // inclusive cumsum (reference output 0)
    offsets[tid] = v - c;         // exclusive offsets for scatter
}

// ---------------------------------------------------------------------------
// Stable LSD radix over depth bits (key bits [16,48)), 4 passes of 8 bits.
// k_rank: block-stable local ranks (ballot-based) into key bits [48,64)
//         + per-block digit histogram bh[blk*256 + d].
// Element order: idx = blk*1024 + q*256 + tid; rank rounds follow (q, tid).
// ---------------------------------------------------------------------------
template<int SHIFT>
__global__ __launch_bounds__(256) void k_rank(
    u64* __restrict__ keys, u32* __restrict__ bh)
{
    __shared__ u32 running[256];
    __shared__ u32 wh[4][256];
    int tid = threadIdx.x, lane = tid & 63, wave = tid >> 6;
    int base = blockIdx.x * 1024;
    u64 lmask = (1ull << lane) - 1;
    u64 k[4]; u32 rk[4];
    #pragma unroll
    for (int q = 0; q < 4; ++q) k[q] = keys[base + q * 256 + tid];
    running[tid] = 0;
    #pragma unroll
    for (int w = 0; w < 4; ++w) wh[w][tid] = 0;
    __syncthreads();                         // zero + running visible
    #pragma unroll
    for (int q = 0; q < 4; ++q) {
        u32 d = (u32)(k[q] >> SHIFT) & 255u;
        u64 m = ~0ull;
        #pragma unroll
        for (int b = 0; b < 8; ++b) {
            u64 bal = __ballot((d >> b) & 1u);
            m &= ((d >> b) & 1u) ? bal : ~bal;
        }
        u32 riw = (u32)__popcll(m & lmask);   // rank among same-digit in wave
        if (riw == 0) wh[wave][d] = (u32)__popcll(m);  // wave-digit count
        __syncthreads();                      // leader writes visible
        u32 off = running[d] + riw;
        for (int w = 0; w < wave; ++w) off += wh[w][d];
        rk[q] = off;
        __syncthreads();                      // reads done before update/zero
        running[tid] += wh[0][tid] + wh[1][tid] + wh[2][tid] + wh[3][tid];
        wh[0][tid] = 0; wh[1][tid] = 0; wh[2][tid] = 0; wh[3][tid] = 0;
        __syncthreads();                      // update+zero visible (next round)
    }
    bh[blockIdx.x * 256 + tid] = running[tid];
    #pragma unroll
    for (int q = 0; q < 4; ++q)
        keys[base + q * 256 + tid] = k[q] | ((u64)rk[q] << 48);
}

// k_scatter: each block redundantly derives its per-digit base from bh
// (global digit excl-scan + sum over earlier blocks), then scatters.
// LAST pass writes the compact entries array directly.
template<int SHIFT, bool LAST>
__global__ __launch_bounds__(256) void k_scatter(
    const u64* __restrict__ src, const u32* __restrict__ bh,
    u64* __restrict__ dst, const u32* __restrict__ bounds,
    u32* __restrict__ entries)
{
    __shared__ u32 loff[256];
    __shared__ u32 wsum[4];
    int tid = threadIdx.x, lane = tid & 63, wave = tid >> 6;
    int blk = blockIdx.x;

    u32 part = 0, tot = 0;
    for (int b = 0; b < RBLK; ++b) {
        u32 h = bh[b * 256 + tid];           // coalesced row per iteration
        part += (b < blk) ? h : 0;
        tot += h;
    }
    // exclusive scan of per-digit totals across 256 threads
    u32 v = tot;
    #pragma unroll
    for (int d = 1; d < 64; d <<= 1) {
        u32 t = __shfl_up(v, d, 64);
        if (lane >= d) v += t;
    }
    if (lane == 63) wsum[wave] = v;
    __syncthreads();
    u32 add = 0;
    for (int w = 0; w < wave; ++w) add += wsum[w];
    loff[tid] = (v + add - tot) + part;      // digit base for this block
    __syncthreads();

    int base = blk * 1024;
    #pragma unroll
    for (int q = 0; q < 4; ++q) {
        u64 key = src[base + q * 256 + tid];
        u32 d = (u32)(key >> SHIFT) & 255u;
        u32 rank = (u32)(key >> 48);
        u32 p = loff[d] + rank;
        if (LAST) {
            u32 prim = (u32)key & 0xFFFFu;
            entries[p] = (bounds[prim] << 16) | prim;
        } else {
            dst[p] = key & 0x0000FFFFFFFFFFFFull;
        }
    }
}

// ---------------------------------------------------------------------------
// Kernel 4: per-tile ordered compaction + -1 tail fill.
// One block per tile; stream the depth-sorted entry array (256 KB,
// L2-resident) and emit members in order. Then all 256 blocks cooperatively
// fill [total, T*N) with -1 (replaces the 64 MB memset dispatch).
// ---------------------------------------------------------------------------
__global__ __launch_bounds__(256) void k_compact(
    const uint4* __restrict__ entries4, const u32* __restrict__ offsets,
    const int* __restrict__ tile_count, int* __restrict__ out_idx)
{
    int tile = blockIdx.x;
    int tx = tile & 15, ty = tile >> 4;
    int tid = threadIdx.x, lane = tid & 63, wave = tid >> 6;
    __shared__ u32 wtot[4];
    u32 base = offsets[tile];
    u64 lmask = (1ull << lane) - 1;

    for (int c = 0; c < NPRIM / 1024; ++c) {   // 64 iterations x 1024 entries
        uint4 e = entries4[c * 256 + tid];     // s = c*1024 + tid*4 + q
        u32 ev[4] = {e.x, e.y, e.z, e.w};
        bool m[4]; u64 bal[4];
        #pragma unroll
        for (int q = 0; q < 4; ++q) {
            u32 b = ev[q] >> 16;
            int xmn = b & 15, xmx = (b >> 4) & 15;
            int ymn = (b >> 8) & 15, ymx = (b >> 12) & 15;
            m[q] = (tx >= xmn) && (tx <= xmx) && (ty >= ymn) && (ty <= ymx);
            bal[q] = __ballot(m[q]);
        }
        u32 wcnt = __popcll(bal[0]) + __popcll(bal[1]) + __popcll(bal[2]) + __popcll(bal[3]);
        if (lane == 0) wtot[wave] = wcnt;
        __syncthreads();
        u32 woff = base;
        for (int w = 0; w < wave; ++w) woff += wtot[w];
        u32 tot = wtot[0] + wtot[1] + wtot[2] + wtot[3];
        u32 pre = __popcll(bal[0] & lmask) + __popcll(bal[1] & lmask)
                + __popcll(bal[2] & lmask) + __popcll(bal[3] & lmask);
        #pragma unroll
        for (int q = 0; q < 4; ++q) {
            if (m[q]) { out_idx[woff + pre] = (int)(ev[q] & 0xFFFFu); pre++; }
        }
        base += tot;
        __syncthreads();   // wtot reused next iteration
    }

    // ---- -1 tail fill: [total, T*N) split across the 256 blocks ----
    u32 total = (u32)tile_count[T_TILES - 1];
    const u32 end = (u32)T_TILES * (u32)NPRIM;
    u32 len = end - total;
    u32 chunk = (len + T_TILES - 1) / T_TILES;
    u32 s = total + (u32)blockIdx.x * chunk;
    if (s < end) {
        u32 e = s + chunk; if (e > end) e = end;
        u32 sa = (s + 3u) & ~3u; if (sa > e) sa = e;
        u32 ea = e & ~3u; if (ea < sa) ea = sa;
        if (tid < (int)(sa - s)) out_idx[s + tid] = -1;   // unaligned head (<4)
        if (tid < (int)(e - ea)) out_idx[ea + tid] = -1;  // unaligned tail (<4)
        int4 m1 = make_int4(-1, -1, -1, -1);
        int4* o4 = (int4*)out_idx;                        // out_idx is 16B aligned
        for (u32 i = sa / 4u + tid; i < ea / 4u; i += 256u) o4[i] = m1;
    }
}

// ---------------------------------------------------------------------------
extern "C" void kernel_launch(void* const* d_in, const int* in_sizes, int n_in,
                              void* d_out, int out_size, void* d_ws, size_t ws_size,
                              hipStream_t stream)
{
    const float2* pos2d  = (const float2*)d_in[0];
    const float*  radius = (const float*)d_in[1];
    const float*  depth  = (const float*)d_in[2];

    int* out32        = (int*)d_out;
    int* tile_count   = out32;             // [256] inclusive cumsum
    int* tile_indices = out32 + T_TILES;   // [256*65536]

    char* ws = (char*)d_ws;
    u64* keys0   = (u64*)(ws);                          // 512 KB
    u64* keys1   = (u64*)(ws + 512 * 1024);             // 512 KB
    u32* bounds  = (u32*)(ws + 1024 * 1024);            // 256 KB
    u32* entries = (u32*)(ws + 1280 * 1024);            // 256 KB
    u32* counts  = (u32*)(ws + 1536 * 1024);            // 1 KB
    u32* offsets = (u32*)(ws + 1536 * 1024 + 4096);     // 1 KB
    u32* bh      = (u32*)(ws + 1536 * 1024 + 8192);     // 64 KB (64 blk x 256 dig)

    hipMemsetAsync(counts, 0, T_TILES * sizeof(u32), stream);

    k_compute<<<RBLK, 256, 0, stream>>>(pos2d, radius, depth, keys0, bounds, counts);
    k_scan<<<1, 256, 0, stream>>>(counts, tile_count, offsets);

    // stable LSD radix on depth bits: key bits [16,48), 4 x 8-bit passes
    k_rank<16><<<RBLK, 256, 0, stream>>>(keys0, bh);
    k_scatter<16, false><<<RBLK, 256, 0, stream>>>(keys0, bh, keys1, bounds, entries);
    k_rank<24><<<RBLK, 256, 0, stream>>>(keys1, bh);
    k_scatter<24, false><<<RBLK, 256, 0, stream>>>(keys1, bh, keys0, bounds, entries);
    k_rank<32><<<RBLK, 256, 0, stream>>>(keys0, bh);
    k_scatter<32, false><<<RBLK, 256, 0, stream>>>(keys0, bh, keys1, bounds, entries);
    k_rank<40><<<RBLK, 256, 0, stream>>>(keys1, bh);
    k_scatter<40, true><<<RBLK, 256, 0, stream>>>(keys1, bh, keys0, bounds, entries);

    k_compact<<<T_TILES, 256, 0, stream>>>((const uint4*)entries, offsets,
                                           tile_count, tile_indices);
}